// Round 7
// baseline (128.112 us; speedup 1.0000x reference)
//
#include <hip/hip_runtime.h>
#include <cstdint>
#include <math.h>

#define KN 128
#define BATCH 16
#define CAND 64

typedef float vfloat4 __attribute__((ext_vector_type(4)));

// Output layout (floats), in reference return order:
// tokens (B,C,4) | rel (B,C,K,K) | acyclic (B,C) | dists (2,B,K,K)
static constexpr size_t TOK_OFF = 0;
static constexpr size_t REL_OFF = (size_t)BATCH * CAND * 4;                     // 4096
static constexpr size_t ACY_OFF = REL_OFF + (size_t)BATCH * CAND * KN * KN;    // 16781312
static constexpr size_t DST_OFF = ACY_OFF + (size_t)BATCH * CAND;              // 16782336

// WS layout (uint32 words):
// [0, 8192)                  base bits: b*512 + r*4 + w
// [8192, 8192 + 1024*1024)   per-bc bit pack: bc*1024 + {0..511 adj rows (r*4+w),
//                                                        512..1023 adjW (w*128+j)}
static constexpr size_t WS_BITS = 0;
static constexpr size_t WS_ADJ  = 8192;

// Diagonal sentinel for dmin: must be large but FINITE after a bf16 round-trip
// (FLT_MAX rounds up to +inf in bf16 -> |inf-inf|=nan in the checker).
#define DIAG_BIG 1.0e30f

// ---------------- Kernel A: base bits prepass + dists (independent work) ----------------
__global__ __launch_bounds__(256) void prep_kernel(const float* __restrict__ A_t,
                                                   const float* __restrict__ feat,
                                                   uint32_t* __restrict__ ws,
                                                   float* __restrict__ out) {
    int t = threadIdx.x;
    // base bits: 4096 half-rows across 1024 blocks
    {
        int tid  = blockIdx.x * 256 + t;
        int wave = tid >> 6;
        int lane = tid & 63;
        int half = wave & 1;
        int row  = wave >> 1;       // b*128 + i
        float v = A_t[(size_t)row * KN + half * 64 + lane];
        unsigned long long m = __ballot(v > 0.5f);
        if (lane == 0) {
            ws[WS_BITS + row * 4 + half * 2]     = (uint32_t)m;
            ws[WS_BITS + row * 4 + half * 2 + 1] = (uint32_t)(m >> 32);
        }
    }
    // dists: 2 rows per block
    {
        int bi = 2 * blockIdx.x + (t >> 7);    // 0..2047 = b*K + i
        int b2 = bi >> 7, i = bi & 127, j = t & 127;
        const float* fi = feat + (size_t)bi * 6;
        const float* fj = feat + (size_t)(b2 * KN + j) * 6;
        float pix = fi[0], piy = fi[1], vix = fi[3], viy = fi[4];
        float pjx = fj[0], pjy = fj[1], vjx = fj[3], vjy = fj[4];
        float dx = pix - pjx, dy = piy - pjy;
        float d = sqrtf(dx * dx + dy * dy);
        float rx = pjx - pix, ry = pjy - piy;
        float vx = vjx - vix, vy = vjy - viy;
        float vv = vx * vx + vy * vy;
        float rv = rx * vx + ry * vy;
        float ts = fminf(fmaxf(-rv / (vv + 1e-6f), 0.0f), 3.0f);
        float mx = rx + vx * ts, my = ry + vy * ts;
        float dmin = (i == j) ? DIAG_BIG : sqrtf(mx * mx + my * my);
        float* o = out + DST_OFF;
        __builtin_nontemporal_store(d,    o + (size_t)(b2 * KN + i) * KN + j);
        __builtin_nontemporal_store(dmin, o + (size_t)((BATCH + b2) * KN + i) * KN + j);
    }
}

// ---------------- Kernel B: bitmask build + tokens + acyclic (no rel write) ----------------
__global__ __launch_bounds__(256) void graph_kernel(const float* __restrict__ cand,
                                                    const float* __restrict__ mask,
                                                    uint32_t* __restrict__ ws,
                                                    float* __restrict__ out) {
    __shared__ uint32_t adj[KN][5];     // candidate bitmask rows, padded stride 5
    __shared__ uint32_t adjW[4][KN];    // word-transpose: adjW[w][j] = adj[j][w]
    __shared__ uint32_t baseB[KN][4];   // base bitmask
    __shared__ int      indegP[2][KN];  // column-sum partials
    __shared__ int      indeg[KN];
    __shared__ uint32_t validW[4];
    __shared__ uint32_t remW[4];
    __shared__ uint32_t removedW[4];
    __shared__ int      minIdx;

    const int t    = threadIdx.x;
    const int lane = t & 63;
    const int wave = t >> 6;
    const int bc   = blockIdx.x;        // b*64 + c
    const int b    = bc >> 6;

    const float* cptr = cand + (size_t)bc * (KN * KN);

    // Issue ALL cand loads first (16-deep MLP), retire under independent work
    float4 c[16];
    const int sub = lane & 31;
    #pragma unroll
    for (int m = 0; m < 16; ++m) {
        int r = (m * 4 + wave) * 2 + (lane >> 5);
        c[m] = ((const float4*)(cptr + (size_t)r * KN))[sub];
    }

    if (t == 0) minIdx = 0x7fffffff;
    if (t < 4)  removedW[t] = 0;

    // base bitmask: 512 words (L2-hot from prep_kernel)
    for (int w = t; w < 512; w += 256) {
        baseB[w >> 2][w & 3] = ws[WS_BITS + b * 512 + w];
    }

    // valid mask
    if (wave < 2) {
        float mv = mask[b * KN + wave * 64 + lane];
        unsigned long long m = __ballot(mv > 0.5f);
        if (lane == 0) {
            validW[wave * 2]     = (uint32_t)m;
            validW[wave * 2 + 1] = (uint32_t)(m >> 32);
        }
    }

    // Pack adjacency bitmask into LDS
    #pragma unroll
    for (int m = 0; m < 16; ++m) {
        int r = (m * 4 + wave) * 2 + (lane >> 5);
        const float4 v = c[m];
        uint32_t nib = (v.x > 0.5f ? 1u : 0u) | (v.y > 0.5f ? 2u : 0u) |
                       (v.z > 0.5f ? 4u : 0u) | (v.w > 0.5f ? 8u : 0u);
        uint32_t word = nib << (4 * (sub & 7));
        word |= __shfl_xor(word, 1);
        word |= __shfl_xor(word, 2);
        word |= __shfl_xor(word, 4);
        if ((lane & 7) == 0) adj[r][sub >> 3] = word;
    }
    __syncthreads();   // adj, baseB, validW ready

    // Word-transpose adjW[w][j] = adj[j][w] (stride 5 coprime 32: conflict-free)
    for (int w = t; w < 512; w += 256) {
        int iw = w >> 7, j = w & 127;
        adjW[iw][j] = adj[j][iw];
    }

    // indeg partials
    {
        int j = t & 127, half = t >> 7;
        uint32_t jw = j >> 5, jb = j & 31;
        int s = 0;
        int i0 = half * 64;
        for (int i = i0; i < i0 + 64; ++i) s += (adj[i][jw] >> jb) & 1u;
        indegP[half][j] = s;
    }

    // Edit-token scan: min linear index of differing upper-triangle pair
    for (int idx = t; idx < 512; idx += 256) {
        int i = idx >> 2, k = idx & 3;
        uint32_t diff = adj[i][k] ^ baseB[i][k];
        if (diff) {
            int base = k * 32;
            uint32_t up, low;
            if (i < base)            { up = diff; low = 0u; }
            else if (i >= base + 31) { up = 0u; low = (i > base + 31) ? diff : (diff & 0x7fffffffu); }
            else {
                int s = i - base;    // 1..30
                up  = diff & (0xffffffffu << (s + 1));
                low = diff & ((1u << s) - 1u);
            }
            int c1 = 0x7fffffff, c2 = 0x7fffffff;
            if (up)  c1 = (i << 7) | (base + __builtin_ctz(up));
            if (low) { int cc = base + __builtin_ctz(low); c2 = (cc << 7) | i; }
            int cm = min(c1, c2);
            if (cm != 0x7fffffff) atomicMin(&minIdx, cm);
        }
    }
    __syncthreads();   // adjW, indegP, minIdx ready

    // Dump compact bit pack for the rel-expansion kernel (L2-resident, 4 KB/bc)
    {
        uint32_t* wadj = ws + WS_ADJ + (size_t)bc * 1024;
        for (int w = t; w < 1024; w += 256) {
            uint32_t val = (w < 512) ? adj[w >> 2][w & 3]
                                     : adjW[(w - 512) >> 7][(w - 512) & 127];
            __builtin_nontemporal_store(val, wadj + w);
        }
    }

    // Combine indeg; zero invalid nodes
    if (t < KN) {
        uint32_t jw = t >> 5, jb = t & 31;
        bool valid = (validW[jw] >> jb) & 1u;
        indeg[t] = valid ? (indegP[0][t] + indegP[1][t]) : 0;
    }

    // Token write
    if (t == 0) {
        float* tok = out + TOK_OFF + (size_t)bc * 4;
        int mi = minIdx;
        if (mi != 0x7fffffff) {
            int i = mi >> 7, j = mi & 127;
            uint32_t b_ij = (baseB[i][j >> 5] >> (j & 31)) & 1u;
            uint32_t b_ji = (baseB[j][i >> 5] >> (i & 31)) & 1u;
            uint32_t c_ij = (adj[i][j >> 5] >> (j & 31)) & 1u;
            uint32_t c_ji = (adj[j][i >> 5] >> (i & 31)) & 1u;
            int prev = (b_ij && !b_ji) ? 1 : ((b_ji && !b_ij) ? 2 : 0);
            int nxt  = (c_ij && !c_ji) ? 1 : ((c_ji && !c_ij) ? 2 : 0);
            tok[0] = (float)i; tok[1] = (float)j; tok[2] = (float)prev; tok[3] = (float)nxt;
        } else {
            tok[0] = 0.f; tok[1] = 0.f; tok[2] = 0.f; tok[3] = 0.f;
        }
    }
    __syncthreads();   // indeg ready

    // Kahn peeling (early-exit is a fixed point => identical to K iterations)
    for (int it = 0; it < KN; ++it) {
        bool rem = false;
        if (t < KN) {
            uint32_t jw = t >> 5, jb = t & 31;
            bool valid   = (validW[jw] >> jb) & 1u;
            bool removed = (removedW[jw] >> jb) & 1u;
            rem = valid && !removed && (indeg[t] == 0);
        }
        unsigned long long m = __ballot(rem);
        if (wave < 2 && lane == 0) {
            remW[wave * 2]     = (uint32_t)m;
            remW[wave * 2 + 1] = (uint32_t)(m >> 32);
        }
        __syncthreads();
        uint32_t r0 = remW[0], r1 = remW[1], r2 = remW[2], r3 = remW[3];
        if ((r0 | r1 | r2 | r3) == 0u) break;
        if (t < 4) removedW[t] |= remW[t];
        if (t < KN) {
            uint32_t jw = t >> 5, jb = t & 31;
            int dec = 0;
            uint32_t rw[4] = {r0, r1, r2, r3};
            for (int w = 0; w < 4; ++w) {
                uint32_t mm = rw[w];
                while (mm) {
                    int i = w * 32 + __builtin_ctz(mm);
                    mm &= mm - 1;
                    dec += (adj[i][jw] >> jb) & 1u;
                }
            }
            indeg[t] -= dec;
        }
        __syncthreads();
    }
    __syncthreads();

    if (t == 0) {
        int rc = __popc(removedW[0]) + __popc(removedW[1]) + __popc(removedW[2]) + __popc(removedW[3]);
        int vc = __popc(validW[0]) + __popc(validW[1]) + __popc(validW[2]) + __popc(validW[3]);
        out[ACY_OFF + bc] = ((rc == vc) || (vc <= 1)) ? 1.0f : 0.0f;
    }
}

// ---------------- Kernel C: rel expansion, 2 blocks per candidate ----------------
__global__ __launch_bounds__(256) void rel_kernel(const uint32_t* __restrict__ ws,
                                                  float* __restrict__ out) {
    __shared__ uint32_t sAdj[64][4];    // rows of this half
    __shared__ uint32_t sAdjT[2][KN];   // transpose words iw in {2h, 2h+1}

    const int t  = threadIdx.x;
    const int bc = blockIdx.x >> 1;
    const int h  = blockIdx.x & 1;      // row half: rows [h*64, h*64+64)

    const uint32_t* wadj = ws + WS_ADJ + (size_t)bc * 1024;

    // Load bits: 512 words (2 per thread), L2-hot
    for (int w = t; w < 512; w += 256) {
        if (w < 256) sAdj[w >> 2][w & 3] = wadj[(h * 64) * 4 + w];
        else {
            int w2 = w - 256;                       // 0..255 -> iw_local*128 + j
            sAdjT[w2 >> 7][w2 & 127] = wadj[512 + (2 * h) * 128 + w2];
        }
    }
    __syncthreads();

    // Expand: rel = cb + 2*cb^T
    float* relp = out + REL_OFF + (size_t)bc * (KN * KN);
    #pragma unroll
    for (int m = 0; m < 8; ++m) {
        int q  = t + 256 * m;        // local float4 index 0..2047
        int il = q >> 5;             // local row 0..63
        int i  = h * 64 + il;        // global row
        int j0 = (q & 31) * 4;
        uint32_t wij = sAdj[il][j0 >> 5];
        int sh = j0 & 31;
        uint32_t ib = i & 31;
        const uint4 wt = *(const uint4*)&sAdjT[il >> 5][j0];   // adj[j0..j0+3][i>>5]
        vfloat4 o;
        o.x = (float)(((wij >> (sh + 0)) & 1u) + 2u * ((wt.x >> ib) & 1u));
        o.y = (float)(((wij >> (sh + 1)) & 1u) + 2u * ((wt.y >> ib) & 1u));
        o.z = (float)(((wij >> (sh + 2)) & 1u) + 2u * ((wt.z >> ib) & 1u));
        o.w = (float)(((wij >> (sh + 3)) & 1u) + 2u * ((wt.w >> ib) & 1u));
        __builtin_nontemporal_store(o, ((vfloat4*)relp) + (size_t)h * 2048 + q);
    }
}

extern "C" void kernel_launch(void* const* d_in, const int* in_sizes, int n_in,
                              void* d_out, int out_size, void* d_ws, size_t ws_size,
                              hipStream_t stream) {
    const float* A_t  = (const float*)d_in[0];
    const float* cand = (const float*)d_in[1];
    const float* feat = (const float*)d_in[2];
    const float* mask = (const float*)d_in[3];
    float* out = (float*)d_out;
    uint32_t* ws = (uint32_t*)d_ws;   // 32 KB bits + 4 MB adj pack

    prep_kernel<<<1024, 256, 0, stream>>>(A_t, feat, ws, out);
    graph_kernel<<<BATCH * CAND, 256, 0, stream>>>(cand, mask, ws, out);
    rel_kernel<<<2 * BATCH * CAND, 256, 0, stream>>>(ws, out);
}